// Round 14
// baseline (315.778 us; speedup 1.0000x reference)
//
#include <hip/hip_runtime.h>
#include <hip/hip_bf16.h>

typedef __hip_bfloat16 bf16;
typedef __attribute__((ext_vector_type(8))) short short8v;
typedef __attribute__((ext_vector_type(4))) float f32x4;

#define BS 32
#define NN 512
#define LL 4096
#define HH 256
#define EE 64
#define WW 8
#define KK 9
#define NE 2048
#define CIN 392
#define KP 416      // CIN padded to 13*32
#define FS 424      // LDS feat row stride (bf16), k2
#define FS2 264     // LDS stage/glu row stride (bf16)
#define LC 4088
#define NM1 511
#define CR 128      // k3f rows per block
#define K2M 64      // k2 rows per block
#define K5M 64      // k5 rows per block

__device__ __forceinline__ float b2f(bf16 v) { return __bfloat162float(v); }
__device__ __forceinline__ float bfr(unsigned short u) {
    union { unsigned int i; float f; } cv; cv.i = ((unsigned int)u) << 16; return cv.f;
}
__device__ __forceinline__ unsigned short f2b(float v) {
    return __builtin_bit_cast(unsigned short, __float2bfloat16(v));
}
__device__ __forceinline__ unsigned int pack2(float a, float b) {
    return (unsigned int)f2b(a) | ((unsigned int)f2b(b) << 16);
}
__device__ __forceinline__ float sigm(float x) {   // fast sigmoid via v_rcp_f32
    return __builtin_amdgcn_rcpf(1.f + __expf(-x));
}

// ---------------- K0: all weight/edge conversions in one kernel ----------------
__global__ void k0_all(const float* __restrict__ pc1w, const float* __restrict__ pc2w,
                       const float* __restrict__ edge, unsigned short* __restrict__ wb,
                       unsigned short* __restrict__ w2b, unsigned short* __restrict__ eb) {
    size_t i = (size_t)blockIdx.x * 256 + threadIdx.x;    // 4,194,304 total
    eb[i] = f2b(edge[i]);
    if (i < (size_t)512 * KP) {
        int row = (int)(i / KP), c = (int)(i % KP);
        wb[i] = (c < CIN) ? f2b(pc1w[(size_t)row * CIN + c]) : 0;
    }
    if (i < (size_t)HH * HH) w2b[i] = f2b(pc2w[i]);
}

// ---------------- K1: LayerNorm over H -> bf16 xn; also writes vn into acc ----------------
__global__ void k1_layernorm(const float* __restrict__ x, const float* __restrict__ ln_g,
                             const float* __restrict__ ln_b, unsigned short* __restrict__ xnb,
                             float* __restrict__ acc) {
    int b = blockIdx.y, n = blockIdx.x, t = threadIdx.x;
    size_t base = ((size_t)(b * NN + n)) * HH;
    float v = x[base + t];
    __shared__ float s1[4], s2[4], mv[2];
    float a = v, q = v * v;
    #pragma unroll
    for (int o = 32; o > 0; o >>= 1) { a += __shfl_down(a, o, 64); q += __shfl_down(q, o, 64); }
    if ((t & 63) == 0) { s1[t >> 6] = a; s2[t >> 6] = q; }
    __syncthreads();
    if (t == 0) {
        float sa = s1[0] + s1[1] + s1[2] + s1[3];
        float sq = s2[0] + s2[1] + s2[2] + s2[3];
        float mean = sa * (1.0f / 256.0f);
        float var = sq * (1.0f / 256.0f) - mean * mean;
        mv[0] = mean; mv[1] = rsqrtf(var + 1e-5f);
    }
    __syncthreads();
    float outv = (v - mv[0]) * mv[1] * ln_g[t] + ln_b[t];
    xnb[base + t] = f2b(outv);
    if (n == 0) acc[b * HH + t] = outv;   // vn seed for (vn + node_out.sum(1))
}

// ---------------- KB: bins (count + scan + fill) in one kernel, 1 block per b ----------------
__global__ void kb_all(const int* __restrict__ wn, int* __restrict__ offs,
                       int* __restrict__ bins) {
    __shared__ int cnt[NM1];
    __shared__ int cur[NM1];
    __shared__ int ps[256];
    int b = blockIdx.x, t = threadIdx.x;
    for (int i = t; i < NM1; i += 256) cnt[i] = 0;
    __syncthreads();
    for (int l = t; l < LC; l += 256)
        atomicAdd(&cnt[wn[b * LL + l + (KK / 2)]], 1);
    __syncthreads();
    int c0 = (2 * t < NM1)     ? cnt[2 * t]     : 0;
    int c1 = (2 * t + 1 < NM1) ? cnt[2 * t + 1] : 0;
    int pair = c0 + c1;
    ps[t] = pair;
    __syncthreads();
    for (int o = 1; o < 256; o <<= 1) {
        int add = (t >= o) ? ps[t - o] : 0;
        __syncthreads();
        ps[t] += add;
        __syncthreads();
    }
    int ex = ps[t] - pair;
    offs[b * 512 + 2 * t] = ex;
    offs[b * 512 + 2 * t + 1] = ex + c0;
    if (2 * t < NM1)     cur[2 * t]     = ex;
    if (2 * t + 1 < NM1) cur[2 * t + 1] = ex + c0;
    __syncthreads();
    for (int l = t; l < LC; l += 256) {
        int c = wn[b * LL + l + (KK / 2)];
        int slot = atomicAdd(&cur[c], 1);
        bins[b * LC + slot] = l;
    }
}

// ---------------- K2: K2M=64 tile, pc1 MFMA, in-register GLU -> h1 ----------------
// 1-D grid 2048, XCD-swizzled: xcd=id&7 owns batches [xcd*4, xcd*4+4)
__global__ void __launch_bounds__(256, 2)
k2_mfma(const unsigned short* __restrict__ xnb, const unsigned short* __restrict__ edgeb,
        const int* __restrict__ wn, const int* __restrict__ we,
        const float* __restrict__ enc, const unsigned short* __restrict__ wb,
        const float* __restrict__ pc1_b, unsigned short* __restrict__ h1) {
    __shared__ __align__(16) unsigned short smem[K2M * FS];   // 54,272 B; glu reuses (FS2)
    __shared__ int rown[K2M], ein[K2M], eout[K2M];
    int id = blockIdx.x;
    int xcd = id & 7, s = id >> 3;              // s in [0,256)
    int b = xcd * 4 + (s >> 6);                 // 4 batches per XCD
    int l0 = (s & 63) * K2M;
    int t = threadIdx.x;
    int lane = t & 63, wv = t >> 6;
    int l15 = lane & 15, lr = (lane >> 4) & 3, koff = lr * 8;
    int c0 = wv * 64;
    const unsigned short* wrO = wb + ((size_t)(c0 + l15)) * KP + koff;
    const unsigned short* wrG = wb + ((size_t)(HH + c0 + l15)) * KP + koff;

    // preload kk=0 B-frags; L2 round trip hides under staging
    short8v bo0[4], bg0[4], bo1[4], bg1[4];
    #pragma unroll
    for (int n = 0; n < 4; ++n) {
        bo0[n] = *(const short8v*)(wrO + (size_t)n * 16 * KP);
        bg0[n] = *(const short8v*)(wrG + (size_t)n * 16 * KP);
    }

    if (t < K2M) {
        int l = l0 + t;
        rown[t] = wn[b * LL + l] + 1;
        ein[t]  = (l > 0)      ? we[b * (LL - 1) + l - 1] : -1;
        eout[t] = (l < LL - 1) ? we[b * (LL - 1) + l]     : -1;
    }
    __syncthreads();

    // node rows: 64 x 256 bf16
    for (int i = t; i < K2M * 32; i += 256) {
        int r = i >> 5, c = (i & 31) * 8;
        *(uint4*)&smem[r * FS + c] =
            *(const uint4*)(xnb + ((size_t)(b * NN + rown[r])) * HH + c);
    }
    // edge rows: 64 x 16 chunks at cols 256..383
    for (int i = t; i < K2M * 16; i += 256) {
        int r = i >> 4, q = i & 15;
        int idx = (q < 8) ? ein[r] : eout[r];
        uint4 v = {0u, 0u, 0u, 0u};
        if (idx >= 0)
            v = *(const uint4*)(edgeb + ((size_t)(b * NE + idx)) * EE + (q & 7) * 8);
        *(uint4*)&smem[r * FS + HH + q * 8] = v;
    }
    // enc (8 ch) at col 384 + zero pad to col 423
    for (int i = t; i < K2M * 5; i += 256) {
        int r = i / 5, q = i % 5;
        uint4 v = {0u, 0u, 0u, 0u};
        if (q == 0) {
            const float* ep = enc + (size_t)b * WW * LL + (l0 + r);
            v.x = pack2(ep[0], ep[LL]);          v.y = pack2(ep[2 * LL], ep[3 * LL]);
            v.z = pack2(ep[4 * LL], ep[5 * LL]); v.w = pack2(ep[6 * LL], ep[7 * LL]);
        }
        *(uint4*)&smem[r * FS + (HH + 2 * EE) + q * 8] = v;
    }
    __syncthreads();

    f32x4 acc[4][8];   // n<4: out frags, n>=4: gate frags (same wave)
    #pragma unroll
    for (int m = 0; m < 4; ++m)
        #pragma unroll
        for (int n = 0; n < 8; ++n) acc[m][n] = (f32x4){0.f, 0.f, 0.f, 0.f};

    const unsigned short* arow = &smem[l15 * FS + koff];

    // 13 K-steps = 6 ping-pong pairs + tail
    #pragma unroll 1
    for (int p = 0; p < 6; ++p) {
        int kk = 2 * p;
        #pragma unroll
        for (int n = 0; n < 4; ++n) {
            bo1[n] = *(const short8v*)(wrO + (size_t)n * 16 * KP + (kk + 1) * 32);
            bg1[n] = *(const short8v*)(wrG + (size_t)n * 16 * KP + (kk + 1) * 32);
        }
        {
            short8v a[4];
            #pragma unroll
            for (int m = 0; m < 4; ++m)
                a[m] = *(const short8v*)(arow + (size_t)m * 16 * FS + kk * 32);
            #pragma unroll
            for (int m = 0; m < 4; ++m)
                #pragma unroll
                for (int n = 0; n < 4; ++n) {
                    acc[m][n]     = __builtin_amdgcn_mfma_f32_16x16x32_bf16(a[m], bo0[n], acc[m][n], 0, 0, 0);
                    acc[m][n + 4] = __builtin_amdgcn_mfma_f32_16x16x32_bf16(a[m], bg0[n], acc[m][n + 4], 0, 0, 0);
                }
        }
        #pragma unroll
        for (int n = 0; n < 4; ++n) {
            bo0[n] = *(const short8v*)(wrO + (size_t)n * 16 * KP + (kk + 2) * 32);
            bg0[n] = *(const short8v*)(wrG + (size_t)n * 16 * KP + (kk + 2) * 32);
        }
        {
            short8v a[4];
            #pragma unroll
            for (int m = 0; m < 4; ++m)
                a[m] = *(const short8v*)(arow + (size_t)m * 16 * FS + (kk + 1) * 32);
            #pragma unroll
            for (int m = 0; m < 4; ++m)
                #pragma unroll
                for (int n = 0; n < 4; ++n) {
                    acc[m][n]     = __builtin_amdgcn_mfma_f32_16x16x32_bf16(a[m], bo1[n], acc[m][n], 0, 0, 0);
                    acc[m][n + 4] = __builtin_amdgcn_mfma_f32_16x16x32_bf16(a[m], bg1[n], acc[m][n + 4], 0, 0, 0);
                }
        }
    }
    {   // tail kk=12 with set 0
        short8v a[4];
        #pragma unroll
        for (int m = 0; m < 4; ++m)
            a[m] = *(const short8v*)(arow + (size_t)m * 16 * FS + 12 * 32);
        #pragma unroll
        for (int m = 0; m < 4; ++m)
            #pragma unroll
            for (int n = 0; n < 4; ++n) {
                acc[m][n]     = __builtin_amdgcn_mfma_f32_16x16x32_bf16(a[m], bo0[n], acc[m][n], 0, 0, 0);
                acc[m][n + 4] = __builtin_amdgcn_mfma_f32_16x16x32_bf16(a[m], bg0[n], acc[m][n + 4], 0, 0, 0);
            }
    }

    float biasO[4], biasG[4];
    #pragma unroll
    for (int n = 0; n < 4; ++n) {
        biasO[n] = pc1_b[c0 + n * 16 + l15];
        biasG[n] = pc1_b[HH + c0 + n * 16 + l15];
    }

    __syncthreads();            // all waves done reading feat tile; reuse smem as glu[64][FS2]
    unsigned short* glu = smem;
    int cb = c0 + l15;
    #pragma unroll
    for (int m = 0; m < 4; ++m)
        #pragma unroll
        for (int n = 0; n < 4; ++n)
            #pragma unroll
            for (int r = 0; r < 4; ++r) {
                int pos = m * 16 + lr * 4 + r;
                float o = acc[m][n][r] + biasO[n];
                float g = acc[m][n + 4][r] + biasG[n];
                glu[pos * FS2 + cb + n * 16] = f2b(o * sigm(g));
            }
    __syncthreads();
    // coalesced writeout: 64 rows x 256 bf16
    for (int i = t; i < K2M * 32; i += 256) {
        int r = i >> 5, c = (i & 31) * 8;
        *(uint4*)(h1 + ((size_t)(b * LL) + l0 + r) * HH + c) = *(const uint4*)&glu[r * FS2 + c];
    }
}

// ---------------- K3f: depthwise conv K=9 + BN stats, 4-ch vectorized, XCD-swizzled ----------------
// 1-D grid 1024: xcd=id&7, s=id>>3 in [0,128); b = xcd*4 + (s>>5); tile = s&31
__global__ void k3f_conv_stats(const unsigned short* __restrict__ h1, const float* __restrict__ dc_w,
                               unsigned short* __restrict__ h2, float* __restrict__ bnsum,
                               float* __restrict__ bnsumsq) {
    __shared__ float sr[4][HH], qr[4][HH];
    int id = blockIdx.x;
    int xcd = id & 7, s5 = id >> 3;
    int b = xcd * 4 + (s5 >> 5);
    int l0 = (s5 & 31) * CR;
    int t = threadIdx.x;
    int g = t >> 6, c4 = (t & 63) * 4;
    int rows_all = min(CR, LC - l0);
    int r0 = g * (CR / 4);
    int r1 = min(r0 + CR / 4, rows_all);

    float wk[4][KK];
    #pragma unroll
    for (int j = 0; j < 4; ++j)
        #pragma unroll
        for (int k = 0; k < KK; ++k) wk[j][k] = dc_w[(c4 + j) * KK + k];

    float s[4] = {0.f, 0.f, 0.f, 0.f}, q[4] = {0.f, 0.f, 0.f, 0.f};
    if (r0 < r1) {
        const unsigned short* src = h1 + ((size_t)b * LL + l0 + r0) * HH + c4;
        float w[KK][4];
        float nxt[4];
        #pragma unroll
        for (int k = 0; k < KK - 1; ++k) {
            uint2 v = *(const uint2*)(src + (size_t)k * HH);
            w[k][0] = bfr((unsigned short)(v.x & 0xffffu)); w[k][1] = bfr((unsigned short)(v.x >> 16));
            w[k][2] = bfr((unsigned short)(v.y & 0xffffu)); w[k][3] = bfr((unsigned short)(v.y >> 16));
        }
        {
            uint2 v = *(const uint2*)(src + (size_t)(KK - 1) * HH);
            nxt[0] = bfr((unsigned short)(v.x & 0xffffu)); nxt[1] = bfr((unsigned short)(v.x >> 16));
            nxt[2] = bfr((unsigned short)(v.y & 0xffffu)); nxt[3] = bfr((unsigned short)(v.y >> 16));
        }
        for (int i = r0; i < r1; ++i) {
            #pragma unroll
            for (int j = 0; j < 4; ++j) w[KK - 1][j] = nxt[j];
            if (i + 1 < r1) {
                uint2 v = *(const uint2*)(src + (size_t)(i - r0 + KK) * HH);
                nxt[0] = bfr((unsigned short)(v.x & 0xffffu)); nxt[1] = bfr((unsigned short)(v.x >> 16));
                nxt[2] = bfr((unsigned short)(v.y & 0xffffu)); nxt[3] = bfr((unsigned short)(v.y >> 16));
            }
            float o[4];
            #pragma unroll
            for (int j = 0; j < 4; ++j) {
                float v = 0.f;
                #pragma unroll
                for (int k = 0; k < KK; ++k) v += w[k][j] * wk[j][k];
                o[j] = v;
                s[j] += v; q[j] += v * v;
            }
            uint2 ov;
            ov.x = pack2(o[0], o[1]); ov.y = pack2(o[2], o[3]);
            *(uint2*)(h2 + ((size_t)b * LC + l0 + i) * HH + c4) = ov;
            #pragma unroll
            for (int k = 0; k < KK - 1; ++k)
                #pragma unroll
                for (int j = 0; j < 4; ++j) w[k][j] = w[k + 1][j];
        }
    }
    #pragma unroll
    for (int j = 0; j < 4; ++j) { sr[g][c4 + j] = s[j]; qr[g][c4 + j] = q[j]; }
    __syncthreads();
    float ss = sr[0][t] + sr[1][t] + sr[2][t] + sr[3][t];
    float qq = qr[0][t] + qr[1][t] + qr[2][t] + qr[3][t];
    atomicAdd(&bnsum[t], ss);
    atomicAdd(&bnsumsq[t], qq);
}

// ---------------- K5: M=64 tile, BN-finalize fused + BN+SiLU staging + pc2 MFMA -> h3 ----------------
// 1-D grid 2048, XCD-swizzled like k2
__global__ void __launch_bounds__(256, 3)
k5_mfma(const unsigned short* __restrict__ h2, const float* __restrict__ bnsum,
        const float* __restrict__ bnsumsq, const float* __restrict__ bn_g,
        const float* __restrict__ bn_b, const unsigned short* __restrict__ w2b,
        const float* __restrict__ pc2_b, unsigned short* __restrict__ h3) {
    __shared__ __align__(16) unsigned short smem[K5M * FS2];   // 33,792 B
    __shared__ float scl[HH], shl[HH];
    int id = blockIdx.x;
    int xcd = id & 7, s = id >> 3;
    int b = xcd * 4 + (s >> 6);
    int l0 = (s & 63) * K5M;
    int t = threadIdx.x;
    int lane = t & 63, wv = t >> 6;
    int l15 = lane & 15, lr = (lane >> 4) & 3, koff = lr * 8;
    int c0 = wv * 64;
    const unsigned short* wrow = w2b + ((size_t)(c0 + l15)) * HH + koff;

    // preload kk=0 B-frags under the staging phase
    short8v b0[4], b1[4];
    #pragma unroll
    for (int n = 0; n < 4; ++n) b0[n] = *(const short8v*)(wrow + (size_t)n * 16 * HH);

    // BN finalize (redundant per block, deterministic): scale/shift for channel t
    {
        const float M = (float)(BS * LC);
        float mean = bnsum[t] / M;
        float var = bnsumsq[t] / M - mean * mean;
        float rstd = rsqrtf(var + 1e-5f);
        float sc = rstd * bn_g[t];
        scl[t] = sc;
        shl[t] = bn_b[t] - mean * sc;
    }
    __syncthreads();

    // stage: 64 rows x 256 ch, BN+SiLU applied, bf16
    for (int i = t; i < K5M * 32; i += 256) {
        int r = i >> 5, c = (i & 31) * 8;
        int l = l0 + r;
        uint4 out = {0u, 0u, 0u, 0u};
        if (l < LC) {
            uint4 v = *(const uint4*)(h2 + ((size_t)b * LC + l) * HH + c);
            unsigned int vv[4] = {v.x, v.y, v.z, v.w};
            unsigned int oo[4];
            #pragma unroll
            for (int j = 0; j < 4; ++j) {
                float f0 = bfr((unsigned short)(vv[j] & 0xffffu));
                float f1 = bfr((unsigned short)(vv[j] >> 16));
                float a0 = f0 * scl[c + 2 * j]     + shl[c + 2 * j];
                float a1 = f1 * scl[c + 2 * j + 1] + shl[c + 2 * j + 1];
                a0 = a0 * sigm(a0);
                a1 = a1 * sigm(a1);
                oo[j] = pack2(a0, a1);
            }
            out.x = oo[0]; out.y = oo[1]; out.z = oo[2]; out.w = oo[3];
        }
        *(uint4*)&smem[r * FS2 + c] = out;
    }
    __syncthreads();

    f32x4 acc[4][4];
    #pragma unroll
    for (int m = 0; m < 4; ++m)
        #pragma unroll
        for (int n = 0; n < 4; ++n) acc[m][n] = (f32x4){0.f, 0.f, 0.f, 0.f};

    const unsigned short* arow = &smem[l15 * FS2 + koff];

    // 8 K-steps = 4 ping-pong pairs
    #pragma unroll 1
    for (int p = 0; p < 4; ++p) {
        int kk = 2 * p;
        #pragma unroll
        for (int n = 0; n < 4; ++n)
            b1[n] = *(const short8v*)(wrow + (size_t)n * 16 * HH + (kk + 1) * 32);
        {
            short8v a[4];
            #pragma unroll
            for (int m = 0; m < 4; ++m)
                a[m] = *(const short8v*)(arow + (size_t)m * 16 * FS2 + kk * 32);
            #pragma unroll
            for (int m = 0; m < 4; ++m)
                #pragma unroll
                for (int n = 0; n < 4; ++n)
                    acc[m][n] = __builtin_amdgcn_mfma_f32_16x16x32_bf16(a[m], b0[n], acc[m][n], 0, 0, 0);
        }
        if (p < 3) {
            #pragma unroll
            for (int n = 0; n < 4; ++n)
                b0[n] = *(const short8v*)(wrow + (size_t)n * 16 * HH + (kk + 2) * 32);
        }
        {
            short8v a[4];
            #pragma unroll
            for (int m = 0; m < 4; ++m)
                a[m] = *(const short8v*)(arow + (size_t)m * 16 * FS2 + (kk + 1) * 32);
            #pragma unroll
            for (int m = 0; m < 4; ++m)
                #pragma unroll
                for (int n = 0; n < 4; ++n)
                    acc[m][n] = __builtin_amdgcn_mfma_f32_16x16x32_bf16(a[m], b1[n], acc[m][n], 0, 0, 0);
        }
    }

    int chb = c0 + l15;
    float bias[4];
    #pragma unroll
    for (int n = 0; n < 4; ++n) bias[n] = pc2_b[chb + n * 16];

    __syncthreads();            // all ds_reads of the A-tile done
    #pragma unroll
    for (int m = 0; m < 4; ++m)
        #pragma unroll
        for (int n = 0; n < 4; ++n)
            #pragma unroll
            for (int r = 0; r < 4; ++r) {
                int pos = m * 16 + lr * 4 + r;
                smem[pos * FS2 + chb + n * 16] = f2b(acc[m][n][r] + bias[n]);
            }
    __syncthreads();
    for (int i = t; i < K5M * 32; i += 256) {
        int r = i >> 5, c = (i & 31) * 8;
        int l = l0 + r;
        if (l < LC)
            *(uint4*)(h3 + ((size_t)b * LC + l) * HH + c) = *(const uint4*)&smem[r * FS2 + c];
    }
}

// ---------------- K6: gather bins -> node_out = mean; also acc += node_out ----------------
__global__ void k6_gather(const unsigned short* __restrict__ h3, const int* __restrict__ offs,
                          const int* __restrict__ bins, float* __restrict__ node_out,
                          float* __restrict__ acc) {
    int bn = blockIdx.x;          // b*511 + n
    int b = bn / NM1, n = bn % NM1, t = threadIdx.x;
    int s = offs[b * 512 + n], e = offs[b * 512 + n + 1];
    float sum = 0.f;
    for (int i = s; i < e; ++i) {
        int l = bins[b * LC + i];
        sum += bfr(h3[((size_t)b * LC + l) * HH + t]);
    }
    float inv = 1.f / (float)max(e - s, 1);
    float v = sum * inv;
    node_out[(size_t)bn * HH + t] = v;
    atomicAdd(&acc[b * HH + t], v);
}

// ---------------- K7: z = acc @ w1^T ----------------
__global__ void k7_mlp1(const float* __restrict__ acc, const float* __restrict__ w1,
                        float* __restrict__ z) {
    int b = blockIdx.x, t = threadIdx.x;
    __shared__ float a[HH];
    a[t] = acc[b * HH + t];
    __syncthreads();
    const float* w = w1 + (size_t)t * HH;
    float s = 0.f;
    for (int c = 0; c < HH; ++c) s += w[c] * a[c];
    z[b * HH + t] = s;
}

// ---------------- K9: BN2 (redundant stats) + ReLU + @w2^T ----------------
__global__ void k9_mlp2(const float* __restrict__ z, const float* __restrict__ g2,
                        const float* __restrict__ b2v, const float* __restrict__ w2,
                        float* __restrict__ vnout) {
    int b = blockIdx.x, t = threadIdx.x;
    __shared__ float a[HH];
    float m = 0.f, q = 0.f;
    for (int bb = 0; bb < BS; ++bb) {
        float v = z[bb * HH + t];
        m += v; q += v * v;
    }
    m *= (1.0f / BS);
    q = q * (1.0f / BS) - m * m;
    float rstd = rsqrtf(q + 1e-5f);
    float sc = rstd * g2[t];
    float sh = b2v[t] - m * sc;
    a[t] = fmaxf(z[b * HH + t] * sc + sh, 0.f);
    __syncthreads();
    const float* w = w2 + (size_t)t * HH;
    float s = 0.f;
    for (int c = 0; c < HH; ++c) s += w[c] * a[c];
    vnout[b * HH + t] = s;
}

// ---------------- K10: final concat/add, write f32 output ----------------
__global__ void k10_out(const float* __restrict__ vnout, const float* __restrict__ node_out,
                        float* __restrict__ out) {
    int bn = blockIdx.x;          // b*512 + n
    int b = bn >> 9, n = bn & (NN - 1), t = threadIdx.x;
    float vo = vnout[b * HH + t];
    float v = (n == 0) ? vo : node_out[((size_t)b * NM1 + (n - 1)) * HH + t] + vo;
    out[(size_t)bn * HH + t] = v;
}

extern "C" void kernel_launch(void* const* d_in, const int* in_sizes, int n_in,
                              void* d_out, int out_size, void* d_ws, size_t ws_size,
                              hipStream_t stream) {
    const float* x     = (const float*)d_in[0];
    const float* edge  = (const float*)d_in[1];
    const int*   wn    = (const int*)d_in[2];
    const int*   we    = (const int*)d_in[3];
    const float* enc   = (const float*)d_in[4];
    const float* ln_g  = (const float*)d_in[5];
    const float* ln_b  = (const float*)d_in[6];
    const float* pc1_w = (const float*)d_in[7];
    const float* pc1_b = (const float*)d_in[8];
    const float* dc_w  = (const float*)d_in[9];
    const float* bn_g  = (const float*)d_in[10];
    const float* bn_b  = (const float*)d_in[11];
    const float* pc2_w = (const float*)d_in[12];
    const float* pc2_b = (const float*)d_in[13];
    const float* w1    = (const float*)d_in[14];
    const float* g2    = (const float*)d_in[15];
    const float* b2v   = (const float*)d_in[16];
    const float* w2    = (const float*)d_in[17];

    char* ws = (char*)d_ws;
    // layout (bytes):
    unsigned short* xnb   = (unsigned short*)(ws + 0);          //  8,388,608
    unsigned short* wbf   = (unsigned short*)(ws + 8388608);    //    425,984
    unsigned short* h1    = (unsigned short*)(ws + 8814592);    // 67,108,864  (h3 aliases after k3f)
    unsigned short* h3    = h1;
    unsigned short* h2    = (unsigned short*)(ws + 75923456);   // 66,977,792
    float* node_out = (float*)(ws + 142901248);                 // 16,744,448  (edgeb aliases before k6)
    unsigned short* edgeb = (unsigned short*)(ws + 142901248);  //  8,388,608  (dead after k2)
    float* bnsum   = (float*)(ws + 159711104);                  //      1,024 [memset]
    float* bnsumsq = (float*)(ws + 159712128);                  //      1,024 [memset]
    float* acc     = (float*)(ws + 159713152);                  //     32,768 [K1 overwrites]
    float* z       = (float*)(ws + 159747968);                  //     32,768
    float* vnout   = (float*)(ws + 159780736);                  //     32,768
    unsigned short* w2b = (unsigned short*)(ws + 159813504);    //    131,072
    int*   offs    = (int*)(ws + 159944576);                    //     65,536
    int*   bins    = (int*)(ws + 160075520);                    //    523,264
    // total = 160,598,784 bytes

    // zero bnsum + bnsumsq every call (graph replays don't re-poison)
    hipMemsetAsync(ws + 159711104, 0, 2048, stream);

    k0_all<<<(BS * NE * EE) / 256, 256, 0, stream>>>(pc1_w, pc2_w, edge, wbf, w2b, edgeb);
    k1_layernorm<<<dim3(NN, BS), 256, 0, stream>>>(x, ln_g, ln_b, xnb, acc);
    kb_all<<<BS, 256, 0, stream>>>(wn, offs, bins);
    k2_mfma<<<(LL / K2M) * BS, 256, 0, stream>>>(xnb, edgeb, wn, we, enc, wbf, pc1_b, h1);
    k3f_conv_stats<<<32 * BS, 256, 0, stream>>>(h1, dc_w, h2, bnsum, bnsumsq);
    k5_mfma<<<(LL / K5M) * BS, 256, 0, stream>>>(h2, bnsum, bnsumsq, bn_g, bn_b, w2b, pc2_b, h3);
    k6_gather<<<BS * NM1, 256, 0, stream>>>(h3, offs, bins, node_out, acc);
    k7_mlp1<<<BS, 256, 0, stream>>>(acc, w1, z);
    k9_mlp2<<<BS, 256, 0, stream>>>(z, g2, b2v, w2, vnout);
    k10_out<<<BS * NN, 256, 0, stream>>>(vnout, node_out, (float*)d_out);
}

// Round 15
// 286.459 us; speedup vs baseline: 1.1024x; 1.1024x over previous
//
#include <hip/hip_runtime.h>
#include <hip/hip_bf16.h>

typedef __hip_bfloat16 bf16;
typedef __attribute__((ext_vector_type(8))) short short8v;
typedef __attribute__((ext_vector_type(4))) float f32x4;

#define BS 32
#define NN 512
#define LL 4096
#define HH 256
#define EE 64
#define WW 8
#define KK 9
#define NE 2048
#define CIN 392
#define KP 416      // CIN padded to 13*32
#define FS 424      // LDS feat row stride (bf16), k2
#define FS2 264     // LDS stage/glu row stride (bf16)
#define LC 4088
#define NM1 511
#define CR 128      // k3f rows per block
#define K2M 64      // k2 rows per block
#define K5M 64      // k5 rows per block

__device__ __forceinline__ float b2f(bf16 v) { return __bfloat162float(v); }
__device__ __forceinline__ float bfr(unsigned short u) {
    union { unsigned int i; float f; } cv; cv.i = ((unsigned int)u) << 16; return cv.f;
}
__device__ __forceinline__ unsigned short f2b(float v) {
    return __builtin_bit_cast(unsigned short, __float2bfloat16(v));
}
__device__ __forceinline__ unsigned int pack2(float a, float b) {
    return (unsigned int)f2b(a) | ((unsigned int)f2b(b) << 16);
}
__device__ __forceinline__ float sigm(float x) {   // fast sigmoid via v_rcp_f32
    return __builtin_amdgcn_rcpf(1.f + __expf(-x));
}

// ---------------- K0: all weight/edge conversions in one kernel ----------------
__global__ void k0_all(const float* __restrict__ pc1w, const float* __restrict__ pc2w,
                       const float* __restrict__ edge, unsigned short* __restrict__ wb,
                       unsigned short* __restrict__ w2b, unsigned short* __restrict__ eb) {
    size_t i = (size_t)blockIdx.x * 256 + threadIdx.x;    // 4,194,304 total
    eb[i] = f2b(edge[i]);
    if (i < (size_t)512 * KP) {
        int row = (int)(i / KP), c = (int)(i % KP);
        wb[i] = (c < CIN) ? f2b(pc1w[(size_t)row * CIN + c]) : 0;
    }
    if (i < (size_t)HH * HH) w2b[i] = f2b(pc2w[i]);
}

// ---------------- K1: LayerNorm over H -> bf16 xn; also writes vn into acc ----------------
__global__ void k1_layernorm(const float* __restrict__ x, const float* __restrict__ ln_g,
                             const float* __restrict__ ln_b, unsigned short* __restrict__ xnb,
                             float* __restrict__ acc) {
    int b = blockIdx.y, n = blockIdx.x, t = threadIdx.x;
    size_t base = ((size_t)(b * NN + n)) * HH;
    float v = x[base + t];
    __shared__ float s1[4], s2[4], mv[2];
    float a = v, q = v * v;
    #pragma unroll
    for (int o = 32; o > 0; o >>= 1) { a += __shfl_down(a, o, 64); q += __shfl_down(q, o, 64); }
    if ((t & 63) == 0) { s1[t >> 6] = a; s2[t >> 6] = q; }
    __syncthreads();
    if (t == 0) {
        float sa = s1[0] + s1[1] + s1[2] + s1[3];
        float sq = s2[0] + s2[1] + s2[2] + s2[3];
        float mean = sa * (1.0f / 256.0f);
        float var = sq * (1.0f / 256.0f) - mean * mean;
        mv[0] = mean; mv[1] = rsqrtf(var + 1e-5f);
    }
    __syncthreads();
    float outv = (v - mv[0]) * mv[1] * ln_g[t] + ln_b[t];
    xnb[base + t] = f2b(outv);
    if (n == 0) acc[b * HH + t] = outv;   // vn seed for (vn + node_out.sum(1))
}

// ---------------- KB: bins (count + scan + fill) in one kernel, 1 block per b ----------------
__global__ void kb_all(const int* __restrict__ wn, int* __restrict__ offs,
                       int* __restrict__ bins) {
    __shared__ int cnt[NM1];
    __shared__ int cur[NM1];
    __shared__ int ps[256];
    int b = blockIdx.x, t = threadIdx.x;
    for (int i = t; i < NM1; i += 256) cnt[i] = 0;
    __syncthreads();
    for (int l = t; l < LC; l += 256)
        atomicAdd(&cnt[wn[b * LL + l + (KK / 2)]], 1);
    __syncthreads();
    int c0 = (2 * t < NM1)     ? cnt[2 * t]     : 0;
    int c1 = (2 * t + 1 < NM1) ? cnt[2 * t + 1] : 0;
    int pair = c0 + c1;
    ps[t] = pair;
    __syncthreads();
    for (int o = 1; o < 256; o <<= 1) {
        int add = (t >= o) ? ps[t - o] : 0;
        __syncthreads();
        ps[t] += add;
        __syncthreads();
    }
    int ex = ps[t] - pair;
    offs[b * 512 + 2 * t] = ex;
    offs[b * 512 + 2 * t + 1] = ex + c0;
    if (2 * t < NM1)     cur[2 * t]     = ex;
    if (2 * t + 1 < NM1) cur[2 * t + 1] = ex + c0;
    __syncthreads();
    for (int l = t; l < LC; l += 256) {
        int c = wn[b * LL + l + (KK / 2)];
        int slot = atomicAdd(&cur[c], 1);
        bins[b * LC + slot] = l;
    }
}

// ---------------- K2: K2M=64 tile, pc1 MFMA, in-register GLU -> h1 ----------------
// 1-D grid 2048, XCD-swizzled: xcd=id&7 owns batches [xcd*4, xcd*4+4)
__global__ void __launch_bounds__(256, 2)
k2_mfma(const unsigned short* __restrict__ xnb, const unsigned short* __restrict__ edgeb,
        const int* __restrict__ wn, const int* __restrict__ we,
        const float* __restrict__ enc, const unsigned short* __restrict__ wb,
        const float* __restrict__ pc1_b, unsigned short* __restrict__ h1) {
    __shared__ __align__(16) unsigned short smem[K2M * FS];   // 54,272 B; glu reuses (FS2)
    __shared__ int rown[K2M], ein[K2M], eout[K2M];
    int id = blockIdx.x;
    int xcd = id & 7, s = id >> 3;              // s in [0,256)
    int b = xcd * 4 + (s >> 6);                 // 4 batches per XCD
    int l0 = (s & 63) * K2M;
    int t = threadIdx.x;
    int lane = t & 63, wv = t >> 6;
    int l15 = lane & 15, lr = (lane >> 4) & 3, koff = lr * 8;
    int c0 = wv * 64;
    const unsigned short* wrO = wb + ((size_t)(c0 + l15)) * KP + koff;
    const unsigned short* wrG = wb + ((size_t)(HH + c0 + l15)) * KP + koff;

    // preload kk=0 B-frags; L2 round trip hides under staging
    short8v bo0[4], bg0[4], bo1[4], bg1[4];
    #pragma unroll
    for (int n = 0; n < 4; ++n) {
        bo0[n] = *(const short8v*)(wrO + (size_t)n * 16 * KP);
        bg0[n] = *(const short8v*)(wrG + (size_t)n * 16 * KP);
    }

    if (t < K2M) {
        int l = l0 + t;
        rown[t] = wn[b * LL + l] + 1;
        ein[t]  = (l > 0)      ? we[b * (LL - 1) + l - 1] : -1;
        eout[t] = (l < LL - 1) ? we[b * (LL - 1) + l]     : -1;
    }
    __syncthreads();

    // node rows: 64 x 256 bf16
    for (int i = t; i < K2M * 32; i += 256) {
        int r = i >> 5, c = (i & 31) * 8;
        *(uint4*)&smem[r * FS + c] =
            *(const uint4*)(xnb + ((size_t)(b * NN + rown[r])) * HH + c);
    }
    // edge rows: 64 x 16 chunks at cols 256..383
    for (int i = t; i < K2M * 16; i += 256) {
        int r = i >> 4, q = i & 15;
        int idx = (q < 8) ? ein[r] : eout[r];
        uint4 v = {0u, 0u, 0u, 0u};
        if (idx >= 0)
            v = *(const uint4*)(edgeb + ((size_t)(b * NE + idx)) * EE + (q & 7) * 8);
        *(uint4*)&smem[r * FS + HH + q * 8] = v;
    }
    // enc (8 ch) at col 384 + zero pad to col 423
    for (int i = t; i < K2M * 5; i += 256) {
        int r = i / 5, q = i % 5;
        uint4 v = {0u, 0u, 0u, 0u};
        if (q == 0) {
            const float* ep = enc + (size_t)b * WW * LL + (l0 + r);
            v.x = pack2(ep[0], ep[LL]);          v.y = pack2(ep[2 * LL], ep[3 * LL]);
            v.z = pack2(ep[4 * LL], ep[5 * LL]); v.w = pack2(ep[6 * LL], ep[7 * LL]);
        }
        *(uint4*)&smem[r * FS + (HH + 2 * EE) + q * 8] = v;
    }
    __syncthreads();

    f32x4 acc[4][8];   // n<4: out frags, n>=4: gate frags (same wave)
    #pragma unroll
    for (int m = 0; m < 4; ++m)
        #pragma unroll
        for (int n = 0; n < 8; ++n) acc[m][n] = (f32x4){0.f, 0.f, 0.f, 0.f};

    const unsigned short* arow = &smem[l15 * FS + koff];

    // 13 K-steps = 6 ping-pong pairs + tail
    #pragma unroll 1
    for (int p = 0; p < 6; ++p) {
        int kk = 2 * p;
        #pragma unroll
        for (int n = 0; n < 4; ++n) {
            bo1[n] = *(const short8v*)(wrO + (size_t)n * 16 * KP + (kk + 1) * 32);
            bg1[n] = *(const short8v*)(wrG + (size_t)n * 16 * KP + (kk + 1) * 32);
        }
        {
            short8v a[4];
            #pragma unroll
            for (int m = 0; m < 4; ++m)
                a[m] = *(const short8v*)(arow + (size_t)m * 16 * FS + kk * 32);
            #pragma unroll
            for (int m = 0; m < 4; ++m)
                #pragma unroll
                for (int n = 0; n < 4; ++n) {
                    acc[m][n]     = __builtin_amdgcn_mfma_f32_16x16x32_bf16(a[m], bo0[n], acc[m][n], 0, 0, 0);
                    acc[m][n + 4] = __builtin_amdgcn_mfma_f32_16x16x32_bf16(a[m], bg0[n], acc[m][n + 4], 0, 0, 0);
                }
        }
        #pragma unroll
        for (int n = 0; n < 4; ++n) {
            bo0[n] = *(const short8v*)(wrO + (size_t)n * 16 * KP + (kk + 2) * 32);
            bg0[n] = *(const short8v*)(wrG + (size_t)n * 16 * KP + (kk + 2) * 32);
        }
        {
            short8v a[4];
            #pragma unroll
            for (int m = 0; m < 4; ++m)
                a[m] = *(const short8v*)(arow + (size_t)m * 16 * FS + (kk + 1) * 32);
            #pragma unroll
            for (int m = 0; m < 4; ++m)
                #pragma unroll
                for (int n = 0; n < 4; ++n) {
                    acc[m][n]     = __builtin_amdgcn_mfma_f32_16x16x32_bf16(a[m], bo1[n], acc[m][n], 0, 0, 0);
                    acc[m][n + 4] = __builtin_amdgcn_mfma_f32_16x16x32_bf16(a[m], bg1[n], acc[m][n + 4], 0, 0, 0);
                }
        }
    }
    {   // tail kk=12 with set 0
        short8v a[4];
        #pragma unroll
        for (int m = 0; m < 4; ++m)
            a[m] = *(const short8v*)(arow + (size_t)m * 16 * FS + 12 * 32);
        #pragma unroll
        for (int m = 0; m < 4; ++m)
            #pragma unroll
            for (int n = 0; n < 4; ++n) {
                acc[m][n]     = __builtin_amdgcn_mfma_f32_16x16x32_bf16(a[m], bo0[n], acc[m][n], 0, 0, 0);
                acc[m][n + 4] = __builtin_amdgcn_mfma_f32_16x16x32_bf16(a[m], bg0[n], acc[m][n + 4], 0, 0, 0);
            }
    }

    float biasO[4], biasG[4];
    #pragma unroll
    for (int n = 0; n < 4; ++n) {
        biasO[n] = pc1_b[c0 + n * 16 + l15];
        biasG[n] = pc1_b[HH + c0 + n * 16 + l15];
    }

    __syncthreads();            // all waves done reading feat tile; reuse smem as glu[64][FS2]
    unsigned short* glu = smem;
    int cb = c0 + l15;
    #pragma unroll
    for (int m = 0; m < 4; ++m)
        #pragma unroll
        for (int n = 0; n < 4; ++n)
            #pragma unroll
            for (int r = 0; r < 4; ++r) {
                int pos = m * 16 + lr * 4 + r;
                float o = acc[m][n][r] + biasO[n];
                float g = acc[m][n + 4][r] + biasG[n];
                glu[pos * FS2 + cb + n * 16] = f2b(o * sigm(g));
            }
    __syncthreads();
    // coalesced writeout: 64 rows x 256 bf16
    for (int i = t; i < K2M * 32; i += 256) {
        int r = i >> 5, c = (i & 31) * 8;
        *(uint4*)(h1 + ((size_t)(b * LL) + l0 + r) * HH + c) = *(const uint4*)&glu[r * FS2 + c];
    }
}

// ---------------- K3f: depthwise conv K=9 + BN stats, 4-ch vectorized ----------------
// 256 thr = 64 ch-threads (4 ch each) x 4 row-groups (CR/4 rows each)
__global__ void k3f_conv_stats(const unsigned short* __restrict__ h1, const float* __restrict__ dc_w,
                               unsigned short* __restrict__ h2, float* __restrict__ bnsum,
                               float* __restrict__ bnsumsq) {
    __shared__ float sr[4][HH], qr[4][HH];
    int b = blockIdx.y, l0 = blockIdx.x * CR, t = threadIdx.x;
    int g = t >> 6, c4 = (t & 63) * 4;
    int rows_all = min(CR, LC - l0);
    int r0 = g * (CR / 4);
    int r1 = min(r0 + CR / 4, rows_all);

    float wk[4][KK];
    #pragma unroll
    for (int j = 0; j < 4; ++j)
        #pragma unroll
        for (int k = 0; k < KK; ++k) wk[j][k] = dc_w[(c4 + j) * KK + k];

    float s[4] = {0.f, 0.f, 0.f, 0.f}, q[4] = {0.f, 0.f, 0.f, 0.f};
    if (r0 < r1) {
        const unsigned short* src = h1 + ((size_t)b * LL + l0 + r0) * HH + c4;
        float w[KK][4];
        float nxt[4];
        #pragma unroll
        for (int k = 0; k < KK - 1; ++k) {
            uint2 v = *(const uint2*)(src + (size_t)k * HH);
            w[k][0] = bfr((unsigned short)(v.x & 0xffffu)); w[k][1] = bfr((unsigned short)(v.x >> 16));
            w[k][2] = bfr((unsigned short)(v.y & 0xffffu)); w[k][3] = bfr((unsigned short)(v.y >> 16));
        }
        {
            uint2 v = *(const uint2*)(src + (size_t)(KK - 1) * HH);
            nxt[0] = bfr((unsigned short)(v.x & 0xffffu)); nxt[1] = bfr((unsigned short)(v.x >> 16));
            nxt[2] = bfr((unsigned short)(v.y & 0xffffu)); nxt[3] = bfr((unsigned short)(v.y >> 16));
        }
        for (int i = r0; i < r1; ++i) {
            #pragma unroll
            for (int j = 0; j < 4; ++j) w[KK - 1][j] = nxt[j];
            if (i + 1 < r1) {
                uint2 v = *(const uint2*)(src + (size_t)(i - r0 + KK) * HH);
                nxt[0] = bfr((unsigned short)(v.x & 0xffffu)); nxt[1] = bfr((unsigned short)(v.x >> 16));
                nxt[2] = bfr((unsigned short)(v.y & 0xffffu)); nxt[3] = bfr((unsigned short)(v.y >> 16));
            }
            float o[4];
            #pragma unroll
            for (int j = 0; j < 4; ++j) {
                float v = 0.f;
                #pragma unroll
                for (int k = 0; k < KK; ++k) v += w[k][j] * wk[j][k];
                o[j] = v;
                s[j] += v; q[j] += v * v;
            }
            uint2 ov;
            ov.x = pack2(o[0], o[1]); ov.y = pack2(o[2], o[3]);
            *(uint2*)(h2 + ((size_t)b * LC + l0 + i) * HH + c4) = ov;
            #pragma unroll
            for (int k = 0; k < KK - 1; ++k)
                #pragma unroll
                for (int j = 0; j < 4; ++j) w[k][j] = w[k + 1][j];
        }
    }
    #pragma unroll
    for (int j = 0; j < 4; ++j) { sr[g][c4 + j] = s[j]; qr[g][c4 + j] = q[j]; }
    __syncthreads();
    float ss = sr[0][t] + sr[1][t] + sr[2][t] + sr[3][t];
    float qq = qr[0][t] + qr[1][t] + qr[2][t] + qr[3][t];
    atomicAdd(&bnsum[t], ss);
    atomicAdd(&bnsumsq[t], qq);
}

__global__ void k4b_finalize(const float* __restrict__ bnsum, const float* __restrict__ bnsumsq,
                             const float* __restrict__ bn_g, const float* __restrict__ bn_b,
                             float* __restrict__ bnscale, float* __restrict__ bnshift) {
    int c = threadIdx.x;
    const float M = (float)(BS * LC);
    float mean = bnsum[c] / M;
    float var = bnsumsq[c] / M - mean * mean;
    float rstd = rsqrtf(var + 1e-5f);
    float sc = rstd * bn_g[c];
    bnscale[c] = sc;
    bnshift[c] = bn_b[c] - mean * sc;
}

// ---------------- K5: M=64 tile, BN+SiLU staging + pc2 MFMA (ping-pong B) -> h3 ----------------
// 64 L-rows x 256 out-ch per block; 4 waves; wave wv: M=64, N=64 (ch wv*64)
__global__ void __launch_bounds__(256, 3)
k5_mfma(const unsigned short* __restrict__ h2, const float* __restrict__ bnscale,
        const float* __restrict__ bnshift, const unsigned short* __restrict__ w2b,
        const float* __restrict__ pc2_b, unsigned short* __restrict__ h3) {
    __shared__ __align__(16) unsigned short smem[K5M * FS2];   // 33,792 B
    __shared__ float scl[HH], shl[HH];
    int b = blockIdx.y, l0 = blockIdx.x * K5M, t = threadIdx.x;
    int lane = t & 63, wv = t >> 6;
    int l15 = lane & 15, lr = (lane >> 4) & 3, koff = lr * 8;
    int c0 = wv * 64;
    const unsigned short* wrow = w2b + ((size_t)(c0 + l15)) * HH + koff;

    // preload kk=0 B-frags under the staging phase
    short8v b0[4], b1[4];
    #pragma unroll
    for (int n = 0; n < 4; ++n) b0[n] = *(const short8v*)(wrow + (size_t)n * 16 * HH);

    scl[t] = bnscale[t];
    shl[t] = bnshift[t];
    __syncthreads();

    // stage: 64 rows x 256 ch, BN+SiLU applied, bf16
    for (int i = t; i < K5M * 32; i += 256) {
        int r = i >> 5, c = (i & 31) * 8;
        int l = l0 + r;
        uint4 out = {0u, 0u, 0u, 0u};
        if (l < LC) {
            uint4 v = *(const uint4*)(h2 + ((size_t)b * LC + l) * HH + c);
            unsigned int vv[4] = {v.x, v.y, v.z, v.w};
            unsigned int oo[4];
            #pragma unroll
            for (int j = 0; j < 4; ++j) {
                float f0 = bfr((unsigned short)(vv[j] & 0xffffu));
                float f1 = bfr((unsigned short)(vv[j] >> 16));
                float a0 = f0 * scl[c + 2 * j]     + shl[c + 2 * j];
                float a1 = f1 * scl[c + 2 * j + 1] + shl[c + 2 * j + 1];
                a0 = a0 * sigm(a0);
                a1 = a1 * sigm(a1);
                oo[j] = pack2(a0, a1);
            }
            out.x = oo[0]; out.y = oo[1]; out.z = oo[2]; out.w = oo[3];
        }
        *(uint4*)&smem[r * FS2 + c] = out;
    }
    __syncthreads();

    f32x4 acc[4][4];
    #pragma unroll
    for (int m = 0; m < 4; ++m)
        #pragma unroll
        for (int n = 0; n < 4; ++n) acc[m][n] = (f32x4){0.f, 0.f, 0.f, 0.f};

    const unsigned short* arow = &smem[l15 * FS2 + koff];

    // 8 K-steps = 4 ping-pong pairs
    #pragma unroll 1
    for (int p = 0; p < 4; ++p) {
        int kk = 2 * p;
        #pragma unroll
        for (int n = 0; n < 4; ++n)
            b1[n] = *(const short8v*)(wrow + (size_t)n * 16 * HH + (kk + 1) * 32);
        {
            short8v a[4];
            #pragma unroll
            for (int m = 0; m < 4; ++m)
                a[m] = *(const short8v*)(arow + (size_t)m * 16 * FS2 + kk * 32);
            #pragma unroll
            for (int m = 0; m < 4; ++m)
                #pragma unroll
                for (int n = 0; n < 4; ++n)
                    acc[m][n] = __builtin_amdgcn_mfma_f32_16x16x32_bf16(a[m], b0[n], acc[m][n], 0, 0, 0);
        }
        if (p < 3) {
            #pragma unroll
            for (int n = 0; n < 4; ++n)
                b0[n] = *(const short8v*)(wrow + (size_t)n * 16 * HH + (kk + 2) * 32);
        }
        {
            short8v a[4];
            #pragma unroll
            for (int m = 0; m < 4; ++m)
                a[m] = *(const short8v*)(arow + (size_t)m * 16 * FS2 + (kk + 1) * 32);
            #pragma unroll
            for (int m = 0; m < 4; ++m)
                #pragma unroll
                for (int n = 0; n < 4; ++n)
                    acc[m][n] = __builtin_amdgcn_mfma_f32_16x16x32_bf16(a[m], b1[n], acc[m][n], 0, 0, 0);
        }
    }

    int chb = c0 + l15;
    float bias[4];
    #pragma unroll
    for (int n = 0; n < 4; ++n) bias[n] = pc2_b[chb + n * 16];

    __syncthreads();            // all ds_reads of the A-tile done
    #pragma unroll
    for (int m = 0; m < 4; ++m)
        #pragma unroll
        for (int n = 0; n < 4; ++n)
            #pragma unroll
            for (int r = 0; r < 4; ++r) {
                int pos = m * 16 + lr * 4 + r;
                smem[pos * FS2 + chb + n * 16] = f2b(acc[m][n][r] + bias[n]);
            }
    __syncthreads();
    for (int i = t; i < K5M * 32; i += 256) {
        int r = i >> 5, c = (i & 31) * 8;
        int l = l0 + r;
        if (l < LC)
            *(uint4*)(h3 + ((size_t)b * LC + l) * HH + c) = *(const uint4*)&smem[r * FS2 + c];
    }
}

// ---------------- K6: gather bins -> node_out = mean ----------------
__global__ void k6_gather(const unsigned short* __restrict__ h3, const int* __restrict__ offs,
                          const int* __restrict__ bins, float* __restrict__ node_out) {
    int bn = blockIdx.x;          // b*511 + n
    int b = bn / NM1, n = bn % NM1, t = threadIdx.x;
    int s = offs[b * 512 + n], e = offs[b * 512 + n + 1];
    float sum = 0.f;
    for (int i = s; i < e; ++i) {
        int l = bins[b * LC + i];
        sum += bfr(h3[((size_t)b * LC + l) * HH + t]);
    }
    float inv = 1.f / (float)max(e - s, 1);
    node_out[(size_t)bn * HH + t] = sum * inv;
}

// ---------------- K6b: acc += sum over nodes of node_out (grid-strided partials) ----------------
__global__ void k6b_accsum(const float* __restrict__ node_out, float* __restrict__ acc) {
    int b = blockIdx.y, g = blockIdx.x, t = threadIdx.x;
    int n0 = g * 32, n1 = min(n0 + 32, NM1);
    float s = 0.f;
    for (int n = n0; n < n1; ++n) s += node_out[((size_t)b * NM1 + n) * HH + t];
    atomicAdd(&acc[b * HH + t], s);
}

// ---------------- K7: z = acc @ w1^T ----------------
__global__ void k7_mlp1(const float* __restrict__ acc, const float* __restrict__ w1,
                        float* __restrict__ z) {
    int b = blockIdx.x, t = threadIdx.x;
    __shared__ float a[HH];
    a[t] = acc[b * HH + t];
    __syncthreads();
    const float* w = w1 + (size_t)t * HH;
    float s = 0.f;
    for (int c = 0; c < HH; ++c) s += w[c] * a[c];
    z[b * HH + t] = s;
}

// ---------------- K8: BN over batch + ReLU (in place) ----------------
__global__ void k8_bn2(float* __restrict__ z, const float* __restrict__ g2,
                       const float* __restrict__ b2v) {
    int t = threadIdx.x;
    float vals[BS];
    float m = 0.f, q = 0.f;
    for (int b = 0; b < BS; ++b) {
        float v = z[b * HH + t];
        vals[b] = v; m += v; q += v * v;
    }
    m *= (1.0f / BS);
    q = q * (1.0f / BS) - m * m;
    float rstd = rsqrtf(q + 1e-5f);
    float sc = rstd * g2[t];
    float sh = b2v[t] - m * sc;
    for (int b = 0; b < BS; ++b) z[b * HH + t] = fmaxf(vals[b] * sc + sh, 0.f);
}

// ---------------- K9: vn_out = relu(zn) @ w2^T ----------------
__global__ void k9_mlp2(const float* __restrict__ z, const float* __restrict__ w2,
                        float* __restrict__ vnout) {
    int b = blockIdx.x, t = threadIdx.x;
    __shared__ float a[HH];
    a[t] = z[b * HH + t];
    __syncthreads();
    const float* w = w2 + (size_t)t * HH;
    float s = 0.f;
    for (int c = 0; c < HH; ++c) s += w[c] * a[c];
    vnout[b * HH + t] = s;
}

// ---------------- K10: final concat/add, write f32 output ----------------
__global__ void k10_out(const float* __restrict__ vnout, const float* __restrict__ node_out,
                        float* __restrict__ out) {
    int bn = blockIdx.x;          // b*512 + n
    int b = bn >> 9, n = bn & (NN - 1), t = threadIdx.x;
    float vo = vnout[b * HH + t];
    float v = (n == 0) ? vo : node_out[((size_t)b * NM1 + (n - 1)) * HH + t] + vo;
    out[(size_t)bn * HH + t] = v;
}

extern "C" void kernel_launch(void* const* d_in, const int* in_sizes, int n_in,
                              void* d_out, int out_size, void* d_ws, size_t ws_size,
                              hipStream_t stream) {
    const float* x     = (const float*)d_in[0];
    const float* edge  = (const float*)d_in[1];
    const int*   wn    = (const int*)d_in[2];
    const int*   we    = (const int*)d_in[3];
    const float* enc   = (const float*)d_in[4];
    const float* ln_g  = (const float*)d_in[5];
    const float* ln_b  = (const float*)d_in[6];
    const float* pc1_w = (const float*)d_in[7];
    const float* pc1_b = (const float*)d_in[8];
    const float* dc_w  = (const float*)d_in[9];
    const float* bn_g  = (const float*)d_in[10];
    const float* bn_b  = (const float*)d_in[11];
    const float* pc2_w = (const float*)d_in[12];
    const float* pc2_b = (const float*)d_in[13];
    const float* w1    = (const float*)d_in[14];
    const float* g2    = (const float*)d_in[15];
    const float* b2v   = (const float*)d_in[16];
    const float* w2    = (const float*)d_in[17];

    char* ws = (char*)d_ws;
    // layout (bytes):
    unsigned short* xnb   = (unsigned short*)(ws + 0);          //  8,388,608
    unsigned short* wbf   = (unsigned short*)(ws + 8388608);    //    425,984
    unsigned short* h1    = (unsigned short*)(ws + 8814592);    // 67,108,864  (h3 aliases after k3f)
    unsigned short* h3    = h1;
    unsigned short* h2    = (unsigned short*)(ws + 75923456);   // 66,977,792
    float* node_out = (float*)(ws + 142901248);                 // 16,744,448  (edgeb aliases before k6)
    unsigned short* edgeb = (unsigned short*)(ws + 142901248);  //  8,388,608  (dead after k2)
    float* bnsum   = (float*)(ws + 159711104);                  //      1,024 [memset]
    float* bnsumsq = (float*)(ws + 159712128);                  //      1,024 [memset]
    float* acc     = (float*)(ws + 159713152);                  //     32,768 [K1 overwrites]
    float* bnscale = (float*)(ws + 159745920);                  //      1,024
    float* bnshift = (float*)(ws + 159746944);                  //      1,024
    float* z       = (float*)(ws + 159747968);                  //     32,768
    float* vnout   = (float*)(ws + 159780736);                  //     32,768
    unsigned short* w2b = (unsigned short*)(ws + 159813504);    //    131,072
    int*   offs    = (int*)(ws + 159944576);                    //     65,536
    int*   bins    = (int*)(ws + 160075520);                    //    523,264
    // total = 160,598,784 bytes

    // zero bnsum + bnsumsq every call (graph replays don't re-poison)
    hipMemsetAsync(ws + 159711104, 0, 2048, stream);

    k0_all<<<(BS * NE * EE) / 256, 256, 0, stream>>>(pc1_w, pc2_w, edge, wbf, w2b, edgeb);
    k1_layernorm<<<dim3(NN, BS), 256, 0, stream>>>(x, ln_g, ln_b, xnb, acc);
    kb_all<<<BS, 256, 0, stream>>>(wn, offs, bins);
    k2_mfma<<<(LL / K2M) * BS, 256, 0, stream>>>(xnb, edgeb, wn, we, enc, wbf, pc1_b, h1);
    k3f_conv_stats<<<dim3((LC + CR - 1) / CR, BS), 256, 0, stream>>>(h1, dc_w, h2, bnsum, bnsumsq);
    k4b_finalize<<<1, 256, 0, stream>>>(bnsum, bnsumsq, bn_g, bn_b, bnscale, bnshift);
    k5_mfma<<<dim3((LC + K5M - 1) / K5M, BS), 256, 0, stream>>>(h2, bnscale, bnshift, w2b, pc2_b, h3);
    k6_gather<<<BS * NM1, 256, 0, stream>>>(h3, offs, bins, node_out);
    k6b_accsum<<<dim3(16, BS), 256, 0, stream>>>(node_out, acc);
    k7_mlp1<<<BS, 256, 0, stream>>>(acc, w1, z);
    k8_bn2<<<1, 256, 0, stream>>>(z, g2, b2v);
    k9_mlp2<<<BS, 256, 0, stream>>>(z, w2, vnout);
    k10_out<<<BS * NN, 256, 0, stream>>>(vnout, node_out, (float*)d_out);
}

// Round 16
// 266.428 us; speedup vs baseline: 1.1852x; 1.0752x over previous
//
#include <hip/hip_runtime.h>
#include <hip/hip_bf16.h>

typedef __hip_bfloat16 bf16;
typedef __attribute__((ext_vector_type(8))) short short8v;
typedef __attribute__((ext_vector_type(4))) float f32x4;

#define BS 32
#define NN 512
#define LL 4096
#define HH 256
#define EE 64
#define WW 8
#define KK 9
#define NE 2048
#define CIN 392
#define KP 416      // CIN padded to 13*32
#define FS 424      // LDS feat row stride (bf16), k2
#define FS2 264     // LDS stage/glu row stride (bf16)
#define LC 4088
#define NM1 511
#define CR 128      // k3f rows per block
#define K2M 64      // k2 rows per block
#define K5M 64      // k5 rows per block

__device__ __forceinline__ float b2f(bf16 v) { return __bfloat162float(v); }
__device__ __forceinline__ float bfr(unsigned short u) {
    union { unsigned int i; float f; } cv; cv.i = ((unsigned int)u) << 16; return cv.f;
}
__device__ __forceinline__ unsigned short f2b(float v) {
    return __builtin_bit_cast(unsigned short, __float2bfloat16(v));
}
__device__ __forceinline__ unsigned int pack2(float a, float b) {
    return (unsigned int)f2b(a) | ((unsigned int)f2b(b) << 16);
}
__device__ __forceinline__ float sigm(float x) {   // fast sigmoid via v_rcp_f32
    return __builtin_amdgcn_rcpf(1.f + __expf(-x));
}

// ---------------- K0: all weight/edge conversions in one kernel ----------------
__global__ void k0_all(const float* __restrict__ pc1w, const float* __restrict__ pc2w,
                       const float* __restrict__ edge, unsigned short* __restrict__ wb,
                       unsigned short* __restrict__ w2b, unsigned short* __restrict__ eb) {
    size_t i = (size_t)blockIdx.x * 256 + threadIdx.x;    // 4,194,304 total
    eb[i] = f2b(edge[i]);
    if (i < (size_t)512 * KP) {
        int row = (int)(i / KP), c = (int)(i % KP);
        wb[i] = (c < CIN) ? f2b(pc1w[(size_t)row * CIN + c]) : 0;
    }
    if (i < (size_t)HH * HH) w2b[i] = f2b(pc2w[i]);
}

// ---------------- K1: LayerNorm over H -> bf16 xn; also writes vn into acc ----------------
__global__ void k1_layernorm(const float* __restrict__ x, const float* __restrict__ ln_g,
                             const float* __restrict__ ln_b, unsigned short* __restrict__ xnb,
                             float* __restrict__ acc) {
    int b = blockIdx.y, n = blockIdx.x, t = threadIdx.x;
    size_t base = ((size_t)(b * NN + n)) * HH;
    float v = x[base + t];
    __shared__ float s1[4], s2[4], mv[2];
    float a = v, q = v * v;
    #pragma unroll
    for (int o = 32; o > 0; o >>= 1) { a += __shfl_down(a, o, 64); q += __shfl_down(q, o, 64); }
    if ((t & 63) == 0) { s1[t >> 6] = a; s2[t >> 6] = q; }
    __syncthreads();
    if (t == 0) {
        float sa = s1[0] + s1[1] + s1[2] + s1[3];
        float sq = s2[0] + s2[1] + s2[2] + s2[3];
        float mean = sa * (1.0f / 256.0f);
        float var = sq * (1.0f / 256.0f) - mean * mean;
        mv[0] = mean; mv[1] = rsqrtf(var + 1e-5f);
    }
    __syncthreads();
    float outv = (v - mv[0]) * mv[1] * ln_g[t] + ln_b[t];
    xnb[base + t] = f2b(outv);
    if (n == 0) acc[b * HH + t] = outv;   // vn seed for (vn + node_out.sum(1))
}

// ---------------- KB: bins (count + scan + fill) in one kernel, 1 block per b ----------------
__global__ void kb_all(const int* __restrict__ wn, int* __restrict__ offs,
                       int* __restrict__ bins) {
    __shared__ int cnt[NM1];
    __shared__ int cur[NM1];
    __shared__ int ps[256];
    int b = blockIdx.x, t = threadIdx.x;
    for (int i = t; i < NM1; i += 256) cnt[i] = 0;
    __syncthreads();
    for (int l = t; l < LC; l += 256)
        atomicAdd(&cnt[wn[b * LL + l + (KK / 2)]], 1);
    __syncthreads();
    int c0 = (2 * t < NM1)     ? cnt[2 * t]     : 0;
    int c1 = (2 * t + 1 < NM1) ? cnt[2 * t + 1] : 0;
    int pair = c0 + c1;
    ps[t] = pair;
    __syncthreads();
    for (int o = 1; o < 256; o <<= 1) {
        int add = (t >= o) ? ps[t - o] : 0;
        __syncthreads();
        ps[t] += add;
        __syncthreads();
    }
    int ex = ps[t] - pair;
    offs[b * 512 + 2 * t] = ex;
    offs[b * 512 + 2 * t + 1] = ex + c0;
    if (2 * t < NM1)     cur[2 * t]     = ex;
    if (2 * t + 1 < NM1) cur[2 * t + 1] = ex + c0;
    __syncthreads();
    for (int l = t; l < LC; l += 256) {
        int c = wn[b * LL + l + (KK / 2)];
        int slot = atomicAdd(&cur[c], 1);
        bins[b * LC + slot] = l;
    }
}

// ---------------- K2: K2M=64 tile, pc1 MFMA, in-register GLU -> h1 ----------------
// 1-D grid 2048, XCD-swizzled: xcd=id&7 owns batches [xcd*4, xcd*4+4)
__global__ void __launch_bounds__(256, 2)
k2_mfma(const unsigned short* __restrict__ xnb, const unsigned short* __restrict__ edgeb,
        const int* __restrict__ wn, const int* __restrict__ we,
        const float* __restrict__ enc, const unsigned short* __restrict__ wb,
        const float* __restrict__ pc1_b, unsigned short* __restrict__ h1) {
    __shared__ __align__(16) unsigned short smem[K2M * FS];   // 54,272 B; glu reuses (FS2)
    __shared__ int rown[K2M], ein[K2M], eout[K2M];
    int id = blockIdx.x;
    int xcd = id & 7, s = id >> 3;              // s in [0,256)
    int b = xcd * 4 + (s >> 6);                 // 4 batches per XCD
    int l0 = (s & 63) * K2M;
    int t = threadIdx.x;
    int lane = t & 63, wv = t >> 6;
    int l15 = lane & 15, lr = (lane >> 4) & 3, koff = lr * 8;
    int c0 = wv * 64;
    const unsigned short* wrO = wb + ((size_t)(c0 + l15)) * KP + koff;
    const unsigned short* wrG = wb + ((size_t)(HH + c0 + l15)) * KP + koff;

    // preload kk=0 B-frags; L2 round trip hides under staging
    short8v bo0[4], bg0[4], bo1[4], bg1[4];
    #pragma unroll
    for (int n = 0; n < 4; ++n) {
        bo0[n] = *(const short8v*)(wrO + (size_t)n * 16 * KP);
        bg0[n] = *(const short8v*)(wrG + (size_t)n * 16 * KP);
    }

    if (t < K2M) {
        int l = l0 + t;
        rown[t] = wn[b * LL + l] + 1;
        ein[t]  = (l > 0)      ? we[b * (LL - 1) + l - 1] : -1;
        eout[t] = (l < LL - 1) ? we[b * (LL - 1) + l]     : -1;
    }
    __syncthreads();

    // node rows: 64 x 256 bf16
    for (int i = t; i < K2M * 32; i += 256) {
        int r = i >> 5, c = (i & 31) * 8;
        *(uint4*)&smem[r * FS + c] =
            *(const uint4*)(xnb + ((size_t)(b * NN + rown[r])) * HH + c);
    }
    // edge rows: 64 x 16 chunks at cols 256..383
    for (int i = t; i < K2M * 16; i += 256) {
        int r = i >> 4, q = i & 15;
        int idx = (q < 8) ? ein[r] : eout[r];
        uint4 v = {0u, 0u, 0u, 0u};
        if (idx >= 0)
            v = *(const uint4*)(edgeb + ((size_t)(b * NE + idx)) * EE + (q & 7) * 8);
        *(uint4*)&smem[r * FS + HH + q * 8] = v;
    }
    // enc (8 ch) at col 384 + zero pad to col 423
    for (int i = t; i < K2M * 5; i += 256) {
        int r = i / 5, q = i % 5;
        uint4 v = {0u, 0u, 0u, 0u};
        if (q == 0) {
            const float* ep = enc + (size_t)b * WW * LL + (l0 + r);
            v.x = pack2(ep[0], ep[LL]);          v.y = pack2(ep[2 * LL], ep[3 * LL]);
            v.z = pack2(ep[4 * LL], ep[5 * LL]); v.w = pack2(ep[6 * LL], ep[7 * LL]);
        }
        *(uint4*)&smem[r * FS + (HH + 2 * EE) + q * 8] = v;
    }
    __syncthreads();

    f32x4 acc[4][8];   // n<4: out frags, n>=4: gate frags (same wave)
    #pragma unroll
    for (int m = 0; m < 4; ++m)
        #pragma unroll
        for (int n = 0; n < 8; ++n) acc[m][n] = (f32x4){0.f, 0.f, 0.f, 0.f};

    const unsigned short* arow = &smem[l15 * FS + koff];

    // 13 K-steps = 6 ping-pong pairs + tail
    #pragma unroll 1
    for (int p = 0; p < 6; ++p) {
        int kk = 2 * p;
        #pragma unroll
        for (int n = 0; n < 4; ++n) {
            bo1[n] = *(const short8v*)(wrO + (size_t)n * 16 * KP + (kk + 1) * 32);
            bg1[n] = *(const short8v*)(wrG + (size_t)n * 16 * KP + (kk + 1) * 32);
        }
        {
            short8v a[4];
            #pragma unroll
            for (int m = 0; m < 4; ++m)
                a[m] = *(const short8v*)(arow + (size_t)m * 16 * FS + kk * 32);
            #pragma unroll
            for (int m = 0; m < 4; ++m)
                #pragma unroll
                for (int n = 0; n < 4; ++n) {
                    acc[m][n]     = __builtin_amdgcn_mfma_f32_16x16x32_bf16(a[m], bo0[n], acc[m][n], 0, 0, 0);
                    acc[m][n + 4] = __builtin_amdgcn_mfma_f32_16x16x32_bf16(a[m], bg0[n], acc[m][n + 4], 0, 0, 0);
                }
        }
        #pragma unroll
        for (int n = 0; n < 4; ++n) {
            bo0[n] = *(const short8v*)(wrO + (size_t)n * 16 * KP + (kk + 2) * 32);
            bg0[n] = *(const short8v*)(wrG + (size_t)n * 16 * KP + (kk + 2) * 32);
        }
        {
            short8v a[4];
            #pragma unroll
            for (int m = 0; m < 4; ++m)
                a[m] = *(const short8v*)(arow + (size_t)m * 16 * FS + (kk + 1) * 32);
            #pragma unroll
            for (int m = 0; m < 4; ++m)
                #pragma unroll
                for (int n = 0; n < 4; ++n) {
                    acc[m][n]     = __builtin_amdgcn_mfma_f32_16x16x32_bf16(a[m], bo1[n], acc[m][n], 0, 0, 0);
                    acc[m][n + 4] = __builtin_amdgcn_mfma_f32_16x16x32_bf16(a[m], bg1[n], acc[m][n + 4], 0, 0, 0);
                }
        }
    }
    {   // tail kk=12 with set 0
        short8v a[4];
        #pragma unroll
        for (int m = 0; m < 4; ++m)
            a[m] = *(const short8v*)(arow + (size_t)m * 16 * FS + 12 * 32);
        #pragma unroll
        for (int m = 0; m < 4; ++m)
            #pragma unroll
            for (int n = 0; n < 4; ++n) {
                acc[m][n]     = __builtin_amdgcn_mfma_f32_16x16x32_bf16(a[m], bo0[n], acc[m][n], 0, 0, 0);
                acc[m][n + 4] = __builtin_amdgcn_mfma_f32_16x16x32_bf16(a[m], bg0[n], acc[m][n + 4], 0, 0, 0);
            }
    }

    float biasO[4], biasG[4];
    #pragma unroll
    for (int n = 0; n < 4; ++n) {
        biasO[n] = pc1_b[c0 + n * 16 + l15];
        biasG[n] = pc1_b[HH + c0 + n * 16 + l15];
    }

    __syncthreads();            // all waves done reading feat tile; reuse smem as glu[64][FS2]
    unsigned short* glu = smem;
    int cb = c0 + l15;
    #pragma unroll
    for (int m = 0; m < 4; ++m)
        #pragma unroll
        for (int n = 0; n < 4; ++n)
            #pragma unroll
            for (int r = 0; r < 4; ++r) {
                int pos = m * 16 + lr * 4 + r;
                float o = acc[m][n][r] + biasO[n];
                float g = acc[m][n + 4][r] + biasG[n];
                glu[pos * FS2 + cb + n * 16] = f2b(o * sigm(g));
            }
    __syncthreads();
    // coalesced writeout: 64 rows x 256 bf16
    for (int i = t; i < K2M * 32; i += 256) {
        int r = i >> 5, c = (i & 31) * 8;
        *(uint4*)(h1 + ((size_t)(b * LL) + l0 + r) * HH + c) = *(const uint4*)&glu[r * FS2 + c];
    }
}

// ---------------- K3f: depthwise conv K=9 + BN stats, 4-ch vectorized ----------------
__global__ void k3f_conv_stats(const unsigned short* __restrict__ h1, const float* __restrict__ dc_w,
                               unsigned short* __restrict__ h2, float* __restrict__ bnsum,
                               float* __restrict__ bnsumsq) {
    __shared__ float sr[4][HH], qr[4][HH];
    int b = blockIdx.y, l0 = blockIdx.x * CR, t = threadIdx.x;
    int g = t >> 6, c4 = (t & 63) * 4;
    int rows_all = min(CR, LC - l0);
    int r0 = g * (CR / 4);
    int r1 = min(r0 + CR / 4, rows_all);

    float wk[4][KK];
    #pragma unroll
    for (int j = 0; j < 4; ++j)
        #pragma unroll
        for (int k = 0; k < KK; ++k) wk[j][k] = dc_w[(c4 + j) * KK + k];

    float s[4] = {0.f, 0.f, 0.f, 0.f}, q[4] = {0.f, 0.f, 0.f, 0.f};
    if (r0 < r1) {
        const unsigned short* src = h1 + ((size_t)b * LL + l0 + r0) * HH + c4;
        float w[KK][4];
        float nxt[4];
        #pragma unroll
        for (int k = 0; k < KK - 1; ++k) {
            uint2 v = *(const uint2*)(src + (size_t)k * HH);
            w[k][0] = bfr((unsigned short)(v.x & 0xffffu)); w[k][1] = bfr((unsigned short)(v.x >> 16));
            w[k][2] = bfr((unsigned short)(v.y & 0xffffu)); w[k][3] = bfr((unsigned short)(v.y >> 16));
        }
        {
            uint2 v = *(const uint2*)(src + (size_t)(KK - 1) * HH);
            nxt[0] = bfr((unsigned short)(v.x & 0xffffu)); nxt[1] = bfr((unsigned short)(v.x >> 16));
            nxt[2] = bfr((unsigned short)(v.y & 0xffffu)); nxt[3] = bfr((unsigned short)(v.y >> 16));
        }
        for (int i = r0; i < r1; ++i) {
            #pragma unroll
            for (int j = 0; j < 4; ++j) w[KK - 1][j] = nxt[j];
            if (i + 1 < r1) {
                uint2 v = *(const uint2*)(src + (size_t)(i - r0 + KK) * HH);
                nxt[0] = bfr((unsigned short)(v.x & 0xffffu)); nxt[1] = bfr((unsigned short)(v.x >> 16));
                nxt[2] = bfr((unsigned short)(v.y & 0xffffu)); nxt[3] = bfr((unsigned short)(v.y >> 16));
            }
            float o[4];
            #pragma unroll
            for (int j = 0; j < 4; ++j) {
                float v = 0.f;
                #pragma unroll
                for (int k = 0; k < KK; ++k) v += w[k][j] * wk[j][k];
                o[j] = v;
                s[j] += v; q[j] += v * v;
            }
            uint2 ov;
            ov.x = pack2(o[0], o[1]); ov.y = pack2(o[2], o[3]);
            *(uint2*)(h2 + ((size_t)b * LC + l0 + i) * HH + c4) = ov;
            #pragma unroll
            for (int k = 0; k < KK - 1; ++k)
                #pragma unroll
                for (int j = 0; j < 4; ++j) w[k][j] = w[k + 1][j];
        }
    }
    #pragma unroll
    for (int j = 0; j < 4; ++j) { sr[g][c4 + j] = s[j]; qr[g][c4 + j] = q[j]; }
    __syncthreads();
    float ss = sr[0][t] + sr[1][t] + sr[2][t] + sr[3][t];
    float qq = qr[0][t] + qr[1][t] + qr[2][t] + qr[3][t];
    atomicAdd(&bnsum[t], ss);
    atomicAdd(&bnsumsq[t], qq);
}

// ---------------- K5: BN-finalize (fused) + BN+SiLU staging + pc2 MFMA -> h3 ----------------
// 64 L-rows x 256 out-ch per block; 4 waves; wave wv: M=64, N=64 (ch wv*64)
__global__ void __launch_bounds__(256, 3)
k5_mfma(const unsigned short* __restrict__ h2, const float* __restrict__ bnsum,
        const float* __restrict__ bnsumsq, const float* __restrict__ bn_g,
        const float* __restrict__ bn_b, const unsigned short* __restrict__ w2b,
        const float* __restrict__ pc2_b, unsigned short* __restrict__ h3) {
    __shared__ __align__(16) unsigned short smem[K5M * FS2];   // 33,792 B
    __shared__ float scl[HH], shl[HH];
    int b = blockIdx.y, l0 = blockIdx.x * K5M, t = threadIdx.x;
    int lane = t & 63, wv = t >> 6;
    int l15 = lane & 15, lr = (lane >> 4) & 3, koff = lr * 8;
    int c0 = wv * 64;
    const unsigned short* wrow = w2b + ((size_t)(c0 + l15)) * HH + koff;

    // preload kk=0 B-frags under the staging phase
    short8v b0[4], b1[4];
    #pragma unroll
    for (int n = 0; n < 4; ++n) b0[n] = *(const short8v*)(wrow + (size_t)n * 16 * HH);

    // fused BN finalize (redundant per block, deterministic)
    {
        const float M = (float)(BS * LC);
        float mean = bnsum[t] / M;
        float var = bnsumsq[t] / M - mean * mean;
        float rstd = rsqrtf(var + 1e-5f);
        float sc = rstd * bn_g[t];
        scl[t] = sc;
        shl[t] = bn_b[t] - mean * sc;
    }
    __syncthreads();

    // stage: 64 rows x 256 ch, BN+SiLU applied, bf16
    for (int i = t; i < K5M * 32; i += 256) {
        int r = i >> 5, c = (i & 31) * 8;
        int l = l0 + r;
        uint4 out = {0u, 0u, 0u, 0u};
        if (l < LC) {
            uint4 v = *(const uint4*)(h2 + ((size_t)b * LC + l) * HH + c);
            unsigned int vv[4] = {v.x, v.y, v.z, v.w};
            unsigned int oo[4];
            #pragma unroll
            for (int j = 0; j < 4; ++j) {
                float f0 = bfr((unsigned short)(vv[j] & 0xffffu));
                float f1 = bfr((unsigned short)(vv[j] >> 16));
                float a0 = f0 * scl[c + 2 * j]     + shl[c + 2 * j];
                float a1 = f1 * scl[c + 2 * j + 1] + shl[c + 2 * j + 1];
                a0 = a0 * sigm(a0);
                a1 = a1 * sigm(a1);
                oo[j] = pack2(a0, a1);
            }
            out.x = oo[0]; out.y = oo[1]; out.z = oo[2]; out.w = oo[3];
        }
        *(uint4*)&smem[r * FS2 + c] = out;
    }
    __syncthreads();

    f32x4 acc[4][4];
    #pragma unroll
    for (int m = 0; m < 4; ++m)
        #pragma unroll
        for (int n = 0; n < 4; ++n) acc[m][n] = (f32x4){0.f, 0.f, 0.f, 0.f};

    const unsigned short* arow = &smem[l15 * FS2 + koff];

    // 8 K-steps = 4 ping-pong pairs
    #pragma unroll 1
    for (int p = 0; p < 4; ++p) {
        int kk = 2 * p;
        #pragma unroll
        for (int n = 0; n < 4; ++n)
            b1[n] = *(const short8v*)(wrow + (size_t)n * 16 * HH + (kk + 1) * 32);
        {
            short8v a[4];
            #pragma unroll
            for (int m = 0; m < 4; ++m)
                a[m] = *(const short8v*)(arow + (size_t)m * 16 * FS2 + kk * 32);
            #pragma unroll
            for (int m = 0; m < 4; ++m)
                #pragma unroll
                for (int n = 0; n < 4; ++n)
                    acc[m][n] = __builtin_amdgcn_mfma_f32_16x16x32_bf16(a[m], b0[n], acc[m][n], 0, 0, 0);
        }
        if (p < 3) {
            #pragma unroll
            for (int n = 0; n < 4; ++n)
                b0[n] = *(const short8v*)(wrow + (size_t)n * 16 * HH + (kk + 2) * 32);
        }
        {
            short8v a[4];
            #pragma unroll
            for (int m = 0; m < 4; ++m)
                a[m] = *(const short8v*)(arow + (size_t)m * 16 * FS2 + (kk + 1) * 32);
            #pragma unroll
            for (int m = 0; m < 4; ++m)
                #pragma unroll
                for (int n = 0; n < 4; ++n)
                    acc[m][n] = __builtin_amdgcn_mfma_f32_16x16x32_bf16(a[m], b1[n], acc[m][n], 0, 0, 0);
        }
    }

    int chb = c0 + l15;
    float bias[4];
    #pragma unroll
    for (int n = 0; n < 4; ++n) bias[n] = pc2_b[chb + n * 16];

    __syncthreads();            // all ds_reads of the A-tile done
    #pragma unroll
    for (int m = 0; m < 4; ++m)
        #pragma unroll
        for (int n = 0; n < 4; ++n)
            #pragma unroll
            for (int r = 0; r < 4; ++r) {
                int pos = m * 16 + lr * 4 + r;
                smem[pos * FS2 + chb + n * 16] = f2b(acc[m][n][r] + bias[n]);
            }
    __syncthreads();
    for (int i = t; i < K5M * 32; i += 256) {
        int r = i >> 5, c = (i & 31) * 8;
        int l = l0 + r;
        if (l < LC)
            *(uint4*)(h3 + ((size_t)b * LC + l) * HH + c) = *(const uint4*)&smem[r * FS2 + c];
    }
}

// ---------------- K6: gather bins -> node_out = mean (vectorized: 8 row-groups x 32 lanes x uint4) ----------------
__global__ void k6_gather(const unsigned short* __restrict__ h3, const int* __restrict__ offs,
                          const int* __restrict__ bins, float* __restrict__ node_out) {
    __shared__ float red[8][HH];
    int bn = blockIdx.x;          // b*511 + n
    int b = bn / NM1, n = bn % NM1, t = threadIdx.x;
    int s = offs[b * 512 + n], e = offs[b * 512 + n + 1];
    int g = t >> 5, lane32 = t & 31;
    int c8 = lane32 * 8;
    float sum[8] = {0.f, 0.f, 0.f, 0.f, 0.f, 0.f, 0.f, 0.f};
    for (int i = s + g; i < e; i += 8) {
        int l = bins[b * LC + i];
        uint4 v = *(const uint4*)(h3 + ((size_t)b * LC + l) * HH + c8);
        sum[0] += bfr((unsigned short)(v.x & 0xffffu)); sum[1] += bfr((unsigned short)(v.x >> 16));
        sum[2] += bfr((unsigned short)(v.y & 0xffffu)); sum[3] += bfr((unsigned short)(v.y >> 16));
        sum[4] += bfr((unsigned short)(v.z & 0xffffu)); sum[5] += bfr((unsigned short)(v.z >> 16));
        sum[6] += bfr((unsigned short)(v.w & 0xffffu)); sum[7] += bfr((unsigned short)(v.w >> 16));
    }
    #pragma unroll
    for (int j = 0; j < 8; ++j) red[g][c8 + j] = sum[j];
    __syncthreads();
    float tot = red[0][t] + red[1][t] + red[2][t] + red[3][t]
              + red[4][t] + red[5][t] + red[6][t] + red[7][t];
    float inv = 1.f / (float)max(e - s, 1);
    node_out[(size_t)bn * HH + t] = tot * inv;
}

// ---------------- K6b: acc += sum over nodes of node_out (grid-strided partials) ----------------
__global__ void k6b_accsum(const float* __restrict__ node_out, float* __restrict__ acc) {
    int b = blockIdx.y, g = blockIdx.x, t = threadIdx.x;
    int n0 = g * 32, n1 = min(n0 + 32, NM1);
    float s = 0.f;
    for (int n = n0; n < n1; ++n) s += node_out[((size_t)b * NM1 + n) * HH + t];
    atomicAdd(&acc[b * HH + t], s);
}

// ---------------- K7: z = acc @ w1^T ----------------
__global__ void k7_mlp1(const float* __restrict__ acc, const float* __restrict__ w1,
                        float* __restrict__ z) {
    int b = blockIdx.x, t = threadIdx.x;
    __shared__ float a[HH];
    a[t] = acc[b * HH + t];
    __syncthreads();
    const float* w = w1 + (size_t)t * HH;
    float s = 0.f;
    for (int c = 0; c < HH; ++c) s += w[c] * a[c];
    z[b * HH + t] = s;
}

// ---------------- K9: BN2 (redundant stats, fused) + ReLU + @w2^T ----------------
__global__ void k9_mlp2(const float* __restrict__ z, const float* __restrict__ g2,
                        const float* __restrict__ b2v, const float* __restrict__ w2,
                        float* __restrict__ vnout) {
    int b = blockIdx.x, t = threadIdx.x;
    __shared__ float a[HH];
    float m = 0.f, q = 0.f;
    for (int bb = 0; bb < BS; ++bb) {
        float v = z[bb * HH + t];
        m += v; q += v * v;
    }
    m *= (1.0f / BS);
    q = q * (1.0f / BS) - m * m;
    float rstd = rsqrtf(q + 1e-5f);
    float sc = rstd * g2[t];
    float sh = b2v[t] - m * sc;
    a[t] = fmaxf(z[b * HH + t] * sc + sh, 0.f);
    __syncthreads();
    const float* w = w2 + (size_t)t * HH;
    float s = 0.f;
    for (int c = 0; c < HH; ++c) s += w[c] * a[c];
    vnout[b * HH + t] = s;
}

// ---------------- K10: final concat/add, write f32 output ----------------
__global__ void k10_out(const float* __restrict__ vnout, const float* __restrict__ node_out,
                        float* __restrict__ out) {
    int bn = blockIdx.x;          // b*512 + n
    int b = bn >> 9, n = bn & (NN - 1), t = threadIdx.x;
    float vo = vnout[b * HH + t];
    float v = (n == 0) ? vo : node_out[((size_t)b * NM1 + (n - 1)) * HH + t] + vo;
    out[(size_t)bn * HH + t] = v;
}

extern "C" void kernel_launch(void* const* d_in, const int* in_sizes, int n_in,
                              void* d_out, int out_size, void* d_ws, size_t ws_size,
                              hipStream_t stream) {
    const float* x     = (const float*)d_in[0];
    const float* edge  = (const float*)d_in[1];
    const int*   wn    = (const int*)d_in[2];
    const int*   we    = (const int*)d_in[3];
    const float* enc   = (const float*)d_in[4];
    const float* ln_g  = (const float*)d_in[5];
    const float* ln_b  = (const float*)d_in[6];
    const float* pc1_w = (const float*)d_in[7];
    const float* pc1_b = (const float*)d_in[8];
    const float* dc_w  = (const float*)d_in[9];
    const float* bn_g  = (const float*)d_in[10];
    const float* bn_b  = (const float*)d_in[11];
    const float* pc2_w = (const float*)d_in[12];
    const float* pc2_b = (const float*)d_in[13];
    const float* w1    = (const float*)d_in[14];
    const float* g2    = (const float*)d_in[15];
    const float* b2v   = (const float*)d_in[16];
    const float* w2    = (const float*)d_in[17];

    char* ws = (char*)d_ws;
    // layout (bytes):
    unsigned short* xnb   = (unsigned short*)(ws + 0);          //  8,388,608
    unsigned short* wbf   = (unsigned short*)(ws + 8388608);    //    425,984
    unsigned short* h1    = (unsigned short*)(ws + 8814592);    // 67,108,864  (h3 aliases after k3f)
    unsigned short* h3    = h1;
    unsigned short* h2    = (unsigned short*)(ws + 75923456);   // 66,977,792
    float* node_out = (float*)(ws + 142901248);                 // 16,744,448  (edgeb aliases before k6)
    unsigned short* edgeb = (unsigned short*)(ws + 142901248);  //  8,388,608  (dead after k2)
    float* bnsum   = (float*)(ws + 159711104);                  //      1,024 [memset]
    float* bnsumsq = (float*)(ws + 159712128);                  //      1,024 [memset]
    float* acc     = (float*)(ws + 159713152);                  //     32,768 [K1 overwrites]
    float* z       = (float*)(ws + 159747968);                  //     32,768
    float* vnout   = (float*)(ws + 159780736);                  //     32,768
    unsigned short* w2b = (unsigned short*)(ws + 159813504);    //    131,072
    int*   offs    = (int*)(ws + 159944576);                    //     65,536
    int*   bins    = (int*)(ws + 160075520);                    //    523,264
    // total = 160,598,784 bytes

    // zero bnsum + bnsumsq every call (graph replays don't re-poison)
    hipMemsetAsync(ws + 159711104, 0, 2048, stream);

    k0_all<<<(BS * NE * EE) / 256, 256, 0, stream>>>(pc1_w, pc2_w, edge, wbf, w2b, edgeb);
    k1_layernorm<<<dim3(NN, BS), 256, 0, stream>>>(x, ln_g, ln_b, xnb, acc);
    kb_all<<<BS, 256, 0, stream>>>(wn, offs, bins);
    k2_mfma<<<(LL / K2M) * BS, 256, 0, stream>>>(xnb, edgeb, wn, we, enc, wbf, pc1_b, h1);
    k3f_conv_stats<<<dim3((LC + CR - 1) / CR, BS), 256, 0, stream>>>(h1, dc_w, h2, bnsum, bnsumsq);
    k5_mfma<<<dim3((LC + K5M - 1) / K5M, BS), 256, 0, stream>>>(h2, bnsum, bnsumsq, bn_g, bn_b, w2b, pc2_b, h3);
    k6_gather<<<BS * NM1, 256, 0, stream>>>(h3, offs, bins, node_out);
    k6b_accsum<<<dim3(16, BS), 256, 0, stream>>>(node_out, acc);
    k7_mlp1<<<BS, 256, 0, stream>>>(acc, w1, z);
    k9_mlp2<<<BS, 256, 0, stream>>>(z, g2, b2v, w2, vnout);
    k10_out<<<BS * NN, 256, 0, stream>>>(vnout, node_out, (float*)d_out);
}